// Round 11
// baseline (1289.367 us; speedup 1.0000x reference)
//
#include <hip/hip_runtime.h>
#include <math.h>

typedef _Float16 half_t;
typedef _Float16 f16x4 __attribute__((ext_vector_type(4)));
typedef _Float16 f16x8 __attribute__((ext_vector_type(8)));
typedef float f32x4 __attribute__((ext_vector_type(4)));

#define D_PROT 512
#define D_TEXT 2048

// ---------------- utility: fp32 -> fp16 convert (vector x4) ----------------
__global__ void k_cvt4(const float* __restrict__ s, half_t* __restrict__ d, int n4) {
    int i = blockIdx.x * 256 + threadIdx.x;
    if (i < n4) {
        float4 v = ((const float4*)s)[i];
        f16x4 o;
        o.x = (_Float16)v.x; o.y = (_Float16)v.y;
        o.z = (_Float16)v.z; o.w = (_Float16)v.w;
        ((f16x4*)d)[i] = o;
    }
}

// ---------------- degree histogram ----------------
__global__ void k_deg(const int* __restrict__ dst, int E, int* __restrict__ deg) {
    int i = blockIdx.x * 256 + threadIdx.x;
    if (i < E) atomicAdd(&deg[dst[i]], 1);
}

__global__ void k_dinv(const int* __restrict__ deg, float* __restrict__ dinv, int n) {
    int i = blockIdx.x * 256 + threadIdx.x;
    if (i < n) dinv[i] = rsqrtf((float)deg[i] + 1.0f);
}

// ---------------- prefix sum ----------------
__global__ void k_blocksum(const int* __restrict__ deg, int* __restrict__ bsum, int n) {
    __shared__ int sd[256];
    int i = blockIdx.x * 256 + threadIdx.x;
    sd[threadIdx.x] = (i < n) ? deg[i] : 0;
    __syncthreads();
    for (int s = 128; s > 0; s >>= 1) {
        if (threadIdx.x < s) sd[threadIdx.x] += sd[threadIdx.x + s];
        __syncthreads();
    }
    if (threadIdx.x == 0) bsum[blockIdx.x] = sd[0];
}

__global__ void k_scan_bsum(const int* __restrict__ bsum, int* __restrict__ boff, int nb) {
    __shared__ int sd[1024];
    int t = threadIdx.x;  // 256
    for (int i = t; i < 1024; i += 256) sd[i] = (i < nb) ? bsum[i] : 0;
    __syncthreads();
    for (int s = 1; s < 1024; s <<= 1) {
        int vals[4];
#pragma unroll
        for (int k = 0; k < 4; k++) {
            int i = t + k * 256;
            vals[k] = (i >= s) ? sd[i - s] : 0;
        }
        __syncthreads();
#pragma unroll
        for (int k = 0; k < 4; k++) sd[t + k * 256] += vals[k];
        __syncthreads();
    }
    for (int i = t; i < nb; i += 256) boff[i] = (i > 0) ? sd[i - 1] : 0;
}

__global__ void k_scan_final(const int* __restrict__ deg, const int* __restrict__ boff,
                             int* __restrict__ rowptr, int n) {
    __shared__ int sd[256];
    int i = blockIdx.x * 256 + threadIdx.x;
    int v = (i < n) ? deg[i] : 0;
    sd[threadIdx.x] = v;
    __syncthreads();
    for (int s = 1; s < 256; s <<= 1) {
        int t2 = (threadIdx.x >= s) ? sd[threadIdx.x - s] : 0;
        __syncthreads();
        sd[threadIdx.x] += t2;
        __syncthreads();
    }
    if (i < n) rowptr[i + 1] = boff[blockIdx.x] + sd[threadIdx.x];
}

// ---------------- CSR fill (atomic append) ----------------
__global__ void k_fill(const int* __restrict__ src, const int* __restrict__ dst, int E,
                       const int* __restrict__ rowptr, int* __restrict__ fill,
                       int* __restrict__ colidx) {
    int i = blockIdx.x * 256 + threadIdx.x;
    if (i < E) {
        int d = dst[i];
        int pos = atomicAdd(&fill[d], 1);
        colidx[rowptr[d] + pos] = src[i];
    }
}

// ---------------- GraphNorm ----------------
__global__ void k_gnreduce(const float* __restrict__ x, float* __restrict__ sums,
                           float* __restrict__ sumsq, int Nn) {
    int t = threadIdx.x;
    int c = t * 2;
    float s0 = 0, s1 = 0, q0 = 0, q1 = 0;
    for (int r = blockIdx.x; r < Nn; r += gridDim.x) {
        float2 v = *(const float2*)(x + (size_t)r * D_PROT + c);
        s0 += v.x; s1 += v.y; q0 += v.x * v.x; q1 += v.y * v.y;
    }
    atomicAdd(&sums[c], s0);  atomicAdd(&sums[c + 1], s1);
    atomicAdd(&sumsq[c], q0); atomicAdd(&sumsq[c + 1], q1);
}

__global__ void k_gnfinal(const float* __restrict__ sums, const float* __restrict__ sumsq,
                          const float* __restrict__ w, const float* __restrict__ b,
                          const float* __restrict__ ms, float* __restrict__ ab, float invN) {
    int d = blockIdx.x * 256 + threadIdx.x;
    if (d < D_PROT) {
        float mean = sums[d] * invN;
        float m2 = sumsq[d] * invN;
        float mm = mean * ms[d];
        float var = m2 - 2.f * mm * mean + mm * mm;
        float rstd = rsqrtf(var + 1e-5f);
        float a = rstd * w[d];
        ab[d] = a;
        ab[D_PROT + d] = b[d] - mm * a;
    }
}

__global__ void k_gnnorm(const float* __restrict__ x, const float* __restrict__ ab,
                         half_t* __restrict__ h, int n4) {
    int i = blockIdx.x * 256 + threadIdx.x;
    if (i < n4) {
        size_t idx = (size_t)i * 4;
        float4 v = *(const float4*)(x + idx);
        int d = (int)(idx & (D_PROT - 1));
        const float* a = ab;
        const float* bb = ab + D_PROT;
        f16x4 o;
        o.x = (_Float16)(v.x * a[d]     + bb[d]);
        o.y = (_Float16)(v.y * a[d + 1] + bb[d + 1]);
        o.z = (_Float16)(v.z * a[d + 2] + bb[d + 2]);
        o.w = (_Float16)(v.w * a[d + 3] + bb[d + 3]);
        *(f16x4*)(h + idx) = o;
    }
}

// ---------------- SGConv aggregation: wave-per-node, 16B/lane, 4-deep ----------------
__global__ void k_agg(const half_t* __restrict__ h, half_t* __restrict__ out,
                      const int* __restrict__ rowptr, const int* __restrict__ colidx,
                      const float* __restrict__ dinv, int Nn) {
    int wid = (blockIdx.x << 2) + (threadIdx.x >> 6);
    if (wid >= Nn) return;
    int lane = threadIdx.x & 63;
    int node = wid;
    float di = dinv[node];
    int beg = rowptr[node], end = rowptr[node + 1];
    const f16x8* hp = (const f16x8*)h;          // row stride = 512/8 = 64
    f16x8 sv = hp[(size_t)node * 64 + lane];
    float dii = di * di;
    float a[8];
#pragma unroll
    for (int j = 0; j < 8; j++) a[j] = (float)sv[j] * dii;
    int e = beg;
    for (; e + 4 <= end; e += 4) {
        int s0 = colidx[e],     s1 = colidx[e + 1];
        int s2 = colidx[e + 2], s3 = colidx[e + 3];
        float w0 = dinv[s0] * di, w1 = dinv[s1] * di;
        float w2 = dinv[s2] * di, w3 = dinv[s3] * di;
        f16x8 v0 = hp[(size_t)s0 * 64 + lane];
        f16x8 v1 = hp[(size_t)s1 * 64 + lane];
        f16x8 v2 = hp[(size_t)s2 * 64 + lane];
        f16x8 v3 = hp[(size_t)s3 * 64 + lane];
#pragma unroll
        for (int j = 0; j < 8; j++)
            a[j] += w0 * (float)v0[j] + w1 * (float)v1[j]
                  + w2 * (float)v2[j] + w3 * (float)v3[j];
    }
    for (; e < end; ++e) {
        int s = colidx[e];
        float wg = dinv[s] * di;
        f16x8 v = hp[(size_t)s * 64 + lane];
#pragma unroll
        for (int j = 0; j < 8; j++) a[j] += wg * (float)v[j];
    }
    f16x8 o;
#pragma unroll
    for (int j = 0; j < 8; j++) o[j] = (_Float16)a[j];
    ((f16x8*)out)[(size_t)node * 64 + lane] = o;
}

// ------------- 256x128 GEMM, BK=32, 8 waves x (64x64), 2 blocks/CU -------------------
// C[M,N] = A[M,K] @ W[N,K]^T + bias. N%128==0, K%32==0.
// Key change vs R3-R10: per-wave acc = 4x4 frags (64 regs) -> total VGPR<=128 ->
// 16 waves/CU; LDS 72KB (triple {A 16KB + B 8KB}) -> 2 blocks/CU. Cross-block
// wave overlap (m114) fills barrier/vmcnt stalls that lockstep couldn't.
// Per tile t (buf t%3): stage {B,Alo,Ahi}(t+2) -> buf (t+2)%3 (3 GLD; that buf's
// reads finished in tile t-1, one barrier back -> WAR safe); 8 ds_reads; 16 MFMA;
// vmcnt(3) (drains t+1, keeps t+2's 3 in flight — never 0); 1 barrier.
// Swizzle (64B rows, verified R8 conflicts=0): read byte ^= (((row>>1)&3)<<4);
// staging source pre-swizzled q ^= (((q>>6)&3)<<3).
#define FENCE() asm volatile("" ::: "memory")
#define BAR()   do { FENCE(); __builtin_amdgcn_s_barrier(); FENCE(); } while (0)
#define WAITV3() asm volatile("s_waitcnt vmcnt(3)" ::: "memory")
#define WAITV0() asm volatile("s_waitcnt vmcnt(0)" ::: "memory")
#define GLD(src, dst) __builtin_amdgcn_global_load_lds( \
    (const __attribute__((address_space(1))) void*)(src), \
    (__attribute__((address_space(3))) void*)(dst), 16, 0, 0)
#define LDF(base, row) \
    (*(const f16x8*)((base) + ((((row) * 64 + fqo)) ^ ((((row) >> 1) & 3) << 4))))
#define MM(mi, nj, A_, B_) \
    acc[mi][nj] = __builtin_amdgcn_mfma_f32_16x16x32_f16(A_, B_, acc[mi][nj], 0, 0, 0)

template <int ACT, typename OUT_T>
__global__ __launch_bounds__(512, 4) void k_gemm8(const half_t* __restrict__ A,
                                                  const half_t* __restrict__ W,
                                                  const float* __restrict__ bias,
                                                  OUT_T* __restrict__ C,
                                                  int M, int N, int K) {
    __shared__ half_t sm[36864];   // 3 bufs x (A 8192 + B 4096 halves) = 72KB
    // XCD-chunked bijective remap, bm-fast within chunk: consecutive blocks on one
    // XCD share a 512KB B panel (L2-resident); A streams once (L3 catches reuse).
    const int gx = gridDim.x;            // N/128
    const int mt = gridDim.y;            // M tiles
    const int nwg = gx * mt;
    int b = blockIdx.y * gx + blockIdx.x;
    int w8 = ((nwg & 7) == 0) ? (b & 7) * (nwg >> 3) + (b >> 3) : b;
    const int bn = (w8 / mt) * 128;
    const int bm = (w8 % mt) * 256;

    const int t = threadIdx.x;
    const int w = t >> 6, lane = t & 63;
    const int fr = lane & 15, fq = lane >> 4;
    const int fqo = fq * 16;
    const int wm = (w >> 1) * 64, wn = (w & 1) * 64;
    const int NT = K >> 5;

    // staging: per-thread source index q in [0,4096) pre-swizzled (R8 involution)
    int q = w * 512 + lane * 8;
    int s = q ^ (((q >> 6) & 3) << 3);
    int r = s >> 5, c = s & 31;
    const half_t* gAlo = A + (size_t)min(bm + r, M - 1) * K + c;
    const half_t* gAhi = A + (size_t)min(bm + 128 + r, M - 1) * K + c;
    const half_t* gB   = W + (size_t)(bn + r) * K + c;
    const int dst0 = w * 512;

#define STAGE(b3, kt) do {                                                     \
    GLD(gB   + (size_t)(kt) * 32, &sm[(b3) * 12288 + 8192 + dst0]);            \
    GLD(gAlo + (size_t)(kt) * 32, &sm[(b3) * 12288 + dst0]);                   \
    GLD(gAhi + (size_t)(kt) * 32, &sm[(b3) * 12288 + 4096 + dst0]);            \
} while (0)

    f32x4 acc[4][4] = {};

    // prologue: tiles 0,1 -> bufs 0,1 (6 loads); vmcnt(3) lands tile0, keeps tile1.
    STAGE(0, 0);
    STAGE(1, (NT > 1) ? 1 : 0);
    WAITV3();
    BAR();

    for (int tt = 0; tt < NT; ++tt) {
        const int cur = tt % 3;
        const int s2 = (tt + 2) % 3;
        const int kt = (tt + 2 < NT) ? tt + 2 : NT - 1;
        const char* smA = (const char*)&sm[cur * 12288];
        const char* smB = smA + 16384;   // 8192 halves
        STAGE(s2, kt);
        f16x8 b0 = LDF(smB, wn + fr);
        f16x8 b1 = LDF(smB, wn + 16 + fr);
        f16x8 b2 = LDF(smB, wn + 32 + fr);
        f16x8 b3 = LDF(smB, wn + 48 + fr);
        __builtin_amdgcn_s_setprio(1);
#pragma unroll
        for (int mi = 0; mi < 4; mi++) {
            f16x8 a = LDF(smA, wm + mi * 16 + fr);
            MM(mi, 0, a, b0); MM(mi, 1, a, b1);
            MM(mi, 2, a, b2); MM(mi, 3, a, b3);
        }
        __builtin_amdgcn_s_setprio(0);
        WAITV3();   // drains tile tt+1's 3 loads; keeps (tt+2)'s 3 in flight
        BAR();
    }
    WAITV0();
#undef STAGE

    // epilogue: D frag mapping col = lane&15, row = (lane>>4)*4 + r
    const int col0 = bn + wn + fr;
#pragma unroll
    for (int mi = 0; mi < 4; mi++) {
        int rb = bm + wm + mi * 16 + fq * 4;
#pragma unroll
        for (int nj = 0; nj < 4; nj++) {
            int col = col0 + nj * 16;
            float bv = bias[col];
#pragma unroll
            for (int rr = 0; rr < 4; rr++) {
                int row = rb + rr;
                if (row < M) {
                    float v = acc[mi][nj][rr] + bv;
                    if (ACT == 1) v = fmaxf(v, 0.f);
                    if (ACT == 2) v = 0.5f * v * (1.f + erff(v * 0.70710678118f));
                    C[(size_t)row * N + col] = (OUT_T)v;
                }
            }
        }
    }
}

// ---------------- launch ----------------
extern "C" void kernel_launch(void* const* d_in, const int* in_sizes, int n_in,
                              void* d_out, int out_size, void* d_ws, size_t ws_size,
                              hipStream_t stream) {
    const float* x     = (const float*)d_in[0];
    const int*   eidx  = (const int*)d_in[1];
    const float* gn_w  = (const float*)d_in[2];
    const float* gn_b  = (const float*)d_in[3];
    const float* gn_ms = (const float*)d_in[4];
    const float* w1    = (const float*)d_in[5];
    const float* b1    = (const float*)d_in[6];
    const float* w2    = (const float*)d_in[7];
    const float* b2    = (const float*)d_in[8];
    const float* p1    = (const float*)d_in[9];
    const float* pb1   = (const float*)d_in[10];
    const float* p2    = (const float*)d_in[11];
    const float* pb2   = (const float*)d_in[12];

    const int Nn = in_sizes[0] / D_PROT;   // 50000
    const int E  = in_sizes[1] / 2;        // 400000
    const int M  = Nn;

    char* ws = (char*)d_ws;
    size_t off = 0;
    auto alloc = [&](size_t bytes) {
        void* p = ws + off;
        off += (bytes + 255) & ~(size_t)255;
        return p;
    };
    half_t* w1h    = (half_t*)alloc((size_t)D_PROT * D_PROT * 2);
    half_t* w2h    = (half_t*)alloc((size_t)D_PROT * D_PROT * 2);
    half_t* p1h    = (half_t*)alloc((size_t)D_TEXT * D_PROT * 2);
    half_t* p2h    = (half_t*)alloc((size_t)D_TEXT * D_TEXT * 2);
    int*    deg    = (int*)alloc((size_t)Nn * 4);
    float*  dinv   = (float*)alloc((size_t)Nn * 4);
    int*    rowptr = (int*)alloc((size_t)(Nn + 1) * 4);
    int*    fillc  = (int*)alloc((size_t)Nn * 4);
    int*    bsum   = (int*)alloc(4096);
    int*    boff   = (int*)alloc(4096);
    int*    colidx = (int*)alloc((size_t)E * 4);
    float*  sums   = (float*)alloc(D_PROT * 4);
    float*  sumsq  = (float*)alloc(D_PROT * 4);
    float*  gnab   = (float*)alloc(2 * D_PROT * 4);
    half_t* buf1   = (half_t*)alloc((size_t)Nn * D_PROT * 2);
    half_t* buf2   = (half_t*)alloc((size_t)Nn * D_PROT * 2);
    half_t* big    = (half_t*)alloc((size_t)Nn * D_TEXT * 2);

    const int* esrc = eidx;
    const int* edst = eidx + E;

    hipMemsetAsync(deg, 0, (size_t)Nn * 4, stream);
    hipMemsetAsync(fillc, 0, (size_t)Nn * 4, stream);
    hipMemsetAsync(rowptr, 0, (size_t)(Nn + 1) * 4, stream);
    hipMemsetAsync(sums, 0, D_PROT * 4, stream);
    hipMemsetAsync(sumsq, 0, D_PROT * 4, stream);

    k_cvt4<<<(D_PROT * D_PROT / 4 + 255) / 256, 256, 0, stream>>>(w1, w1h, D_PROT * D_PROT / 4);
    k_cvt4<<<(D_PROT * D_PROT / 4 + 255) / 256, 256, 0, stream>>>(w2, w2h, D_PROT * D_PROT / 4);
    k_cvt4<<<(D_TEXT * D_PROT / 4 + 255) / 256, 256, 0, stream>>>(p1, p1h, D_TEXT * D_PROT / 4);
    k_cvt4<<<(D_TEXT * D_TEXT / 4 + 255) / 256, 256, 0, stream>>>(p2, p2h, D_TEXT * D_TEXT / 4);

    int eb = (E + 255) / 256;
    int nb = (Nn + 255) / 256;
    k_deg<<<eb, 256, 0, stream>>>(edst, E, deg);
    k_dinv<<<nb, 256, 0, stream>>>(deg, dinv, Nn);
    k_blocksum<<<nb, 256, 0, stream>>>(deg, bsum, Nn);
    k_scan_bsum<<<1, 256, 0, stream>>>(bsum, boff, nb);
    k_scan_final<<<nb, 256, 0, stream>>>(deg, boff, rowptr, Nn);
    k_fill<<<eb, 256, 0, stream>>>(esrc, edst, E, rowptr, fillc, colidx);

    k_gnreduce<<<256, 256, 0, stream>>>(x, sums, sumsq, Nn);
    k_gnfinal<<<2, 256, 0, stream>>>(sums, sumsq, gn_w, gn_b, gn_ms, gnab, 1.0f / (float)Nn);
    int n4 = Nn * D_PROT / 4;
    k_gnnorm<<<(n4 + 255) / 256, 256, 0, stream>>>(x, gnab, buf1, n4);

    const int mt256 = (M + 255) / 256;
    const int aggb = (Nn + 3) / 4;

    // conv1: agg -> gemm+relu
    k_agg<<<aggb, 256, 0, stream>>>(buf1, buf2, rowptr, colidx, dinv, Nn);
    {
        dim3 g(D_PROT / 128, mt256);
        k_gemm8<1, half_t><<<g, 512, 0, stream>>>(buf2, w1h, b1, buf1, M, D_PROT, D_PROT);
    }
    // conv2
    k_agg<<<aggb, 256, 0, stream>>>(buf1, buf2, rowptr, colidx, dinv, Nn);
    {
        dim3 g(D_PROT / 128, mt256);
        k_gemm8<1, half_t><<<g, 512, 0, stream>>>(buf2, w2h, b2, buf1, M, D_PROT, D_PROT);
    }
    // proj1 + gelu
    {
        dim3 g(D_TEXT / 128, mt256);
        k_gemm8<2, half_t><<<g, 512, 0, stream>>>(buf1, p1h, pb1, big, M, D_TEXT, D_PROT);
    }
    // proj2 -> fp32 out
    {
        dim3 g(D_TEXT / 128, mt256);
        k_gemm8<0, float><<<g, 512, 0, stream>>>(big, p2h, pb2, (float*)d_out, M, D_TEXT, D_TEXT);
    }
}

// Round 12
// 1192.682 us; speedup vs baseline: 1.0811x; 1.0811x over previous
//
#include <hip/hip_runtime.h>
#include <math.h>

typedef _Float16 half_t;
typedef _Float16 f16x4 __attribute__((ext_vector_type(4)));
typedef _Float16 f16x8 __attribute__((ext_vector_type(8)));
typedef float f32x4 __attribute__((ext_vector_type(4)));

#define D_PROT 512
#define D_TEXT 2048

// ---------------- utility: fp32 -> fp16 convert (vector x4) ----------------
__global__ void k_cvt4(const float* __restrict__ s, half_t* __restrict__ d, int n4) {
    int i = blockIdx.x * 256 + threadIdx.x;
    if (i < n4) {
        float4 v = ((const float4*)s)[i];
        f16x4 o;
        o.x = (_Float16)v.x; o.y = (_Float16)v.y;
        o.z = (_Float16)v.z; o.w = (_Float16)v.w;
        ((f16x4*)d)[i] = o;
    }
}

// ---------------- degree histogram ----------------
__global__ void k_deg(const int* __restrict__ dst, int E, int* __restrict__ deg) {
    int i = blockIdx.x * 256 + threadIdx.x;
    if (i < E) atomicAdd(&deg[dst[i]], 1);
}

__global__ void k_dinv(const int* __restrict__ deg, float* __restrict__ dinv, int n) {
    int i = blockIdx.x * 256 + threadIdx.x;
    if (i < n) dinv[i] = rsqrtf((float)deg[i] + 1.0f);
}

// ---------------- prefix sum ----------------
__global__ void k_blocksum(const int* __restrict__ deg, int* __restrict__ bsum, int n) {
    __shared__ int sd[256];
    int i = blockIdx.x * 256 + threadIdx.x;
    sd[threadIdx.x] = (i < n) ? deg[i] : 0;
    __syncthreads();
    for (int s = 128; s > 0; s >>= 1) {
        if (threadIdx.x < s) sd[threadIdx.x] += sd[threadIdx.x + s];
        __syncthreads();
    }
    if (threadIdx.x == 0) bsum[blockIdx.x] = sd[0];
}

__global__ void k_scan_bsum(const int* __restrict__ bsum, int* __restrict__ boff, int nb) {
    __shared__ int sd[1024];
    int t = threadIdx.x;  // 256
    for (int i = t; i < 1024; i += 256) sd[i] = (i < nb) ? bsum[i] : 0;
    __syncthreads();
    for (int s = 1; s < 1024; s <<= 1) {
        int vals[4];
#pragma unroll
        for (int k = 0; k < 4; k++) {
            int i = t + k * 256;
            vals[k] = (i >= s) ? sd[i - s] : 0;
        }
        __syncthreads();
#pragma unroll
        for (int k = 0; k < 4; k++) sd[t + k * 256] += vals[k];
        __syncthreads();
    }
    for (int i = t; i < nb; i += 256) boff[i] = (i > 0) ? sd[i - 1] : 0;
}

__global__ void k_scan_final(const int* __restrict__ deg, const int* __restrict__ boff,
                             int* __restrict__ rowptr, int n) {
    __shared__ int sd[256];
    int i = blockIdx.x * 256 + threadIdx.x;
    int v = (i < n) ? deg[i] : 0;
    sd[threadIdx.x] = v;
    __syncthreads();
    for (int s = 1; s < 256; s <<= 1) {
        int t2 = (threadIdx.x >= s) ? sd[threadIdx.x - s] : 0;
        __syncthreads();
        sd[threadIdx.x] += t2;
        __syncthreads();
    }
    if (i < n) rowptr[i + 1] = boff[blockIdx.x] + sd[threadIdx.x];
}

// ---------------- CSR fill (atomic append) ----------------
__global__ void k_fill(const int* __restrict__ src, const int* __restrict__ dst, int E,
                       const int* __restrict__ rowptr, int* __restrict__ fill,
                       int* __restrict__ colidx) {
    int i = blockIdx.x * 256 + threadIdx.x;
    if (i < E) {
        int d = dst[i];
        int pos = atomicAdd(&fill[d], 1);
        colidx[rowptr[d] + pos] = src[i];
    }
}

// ---------------- GraphNorm ----------------
__global__ void k_gnreduce(const float* __restrict__ x, float* __restrict__ sums,
                           float* __restrict__ sumsq, int Nn) {
    int t = threadIdx.x;
    int c = t * 2;
    float s0 = 0, s1 = 0, q0 = 0, q1 = 0;
    for (int r = blockIdx.x; r < Nn; r += gridDim.x) {
        float2 v = *(const float2*)(x + (size_t)r * D_PROT + c);
        s0 += v.x; s1 += v.y; q0 += v.x * v.x; q1 += v.y * v.y;
    }
    atomicAdd(&sums[c], s0);  atomicAdd(&sums[c + 1], s1);
    atomicAdd(&sumsq[c], q0); atomicAdd(&sumsq[c + 1], q1);
}

__global__ void k_gnfinal(const float* __restrict__ sums, const float* __restrict__ sumsq,
                          const float* __restrict__ w, const float* __restrict__ b,
                          const float* __restrict__ ms, float* __restrict__ ab, float invN) {
    int d = blockIdx.x * 256 + threadIdx.x;
    if (d < D_PROT) {
        float mean = sums[d] * invN;
        float m2 = sumsq[d] * invN;
        float mm = mean * ms[d];
        float var = m2 - 2.f * mm * mean + mm * mm;
        float rstd = rsqrtf(var + 1e-5f);
        float a = rstd * w[d];
        ab[d] = a;
        ab[D_PROT + d] = b[d] - mm * a;
    }
}

__global__ void k_gnnorm(const float* __restrict__ x, const float* __restrict__ ab,
                         half_t* __restrict__ h, int n4) {
    int i = blockIdx.x * 256 + threadIdx.x;
    if (i < n4) {
        size_t idx = (size_t)i * 4;
        float4 v = *(const float4*)(x + idx);
        int d = (int)(idx & (D_PROT - 1));
        const float* a = ab;
        const float* bb = ab + D_PROT;
        f16x4 o;
        o.x = (_Float16)(v.x * a[d]     + bb[d]);
        o.y = (_Float16)(v.y * a[d + 1] + bb[d + 1]);
        o.z = (_Float16)(v.z * a[d + 2] + bb[d + 2]);
        o.w = (_Float16)(v.w * a[d + 3] + bb[d + 3]);
        *(f16x4*)(h + idx) = o;
    }
}

// ---------------- SGConv aggregation: wave-per-node, 16B/lane, 4-deep ----------------
__global__ void k_agg(const half_t* __restrict__ h, half_t* __restrict__ out,
                      const int* __restrict__ rowptr, const int* __restrict__ colidx,
                      const float* __restrict__ dinv, int Nn) {
    int wid = (blockIdx.x << 2) + (threadIdx.x >> 6);
    if (wid >= Nn) return;
    int lane = threadIdx.x & 63;
    int node = wid;
    float di = dinv[node];
    int beg = rowptr[node], end = rowptr[node + 1];
    const f16x8* hp = (const f16x8*)h;          // row stride = 512/8 = 64
    f16x8 sv = hp[(size_t)node * 64 + lane];
    float dii = di * di;
    float a[8];
#pragma unroll
    for (int j = 0; j < 8; j++) a[j] = (float)sv[j] * dii;
    int e = beg;
    for (; e + 4 <= end; e += 4) {
        int s0 = colidx[e],     s1 = colidx[e + 1];
        int s2 = colidx[e + 2], s3 = colidx[e + 3];
        float w0 = dinv[s0] * di, w1 = dinv[s1] * di;
        float w2 = dinv[s2] * di, w3 = dinv[s3] * di;
        f16x8 v0 = hp[(size_t)s0 * 64 + lane];
        f16x8 v1 = hp[(size_t)s1 * 64 + lane];
        f16x8 v2 = hp[(size_t)s2 * 64 + lane];
        f16x8 v3 = hp[(size_t)s3 * 64 + lane];
#pragma unroll
        for (int j = 0; j < 8; j++)
            a[j] += w0 * (float)v0[j] + w1 * (float)v1[j]
                  + w2 * (float)v2[j] + w3 * (float)v3[j];
    }
    for (; e < end; ++e) {
        int s = colidx[e];
        float wg = dinv[s] * di;
        f16x8 v = hp[(size_t)s * 64 + lane];
#pragma unroll
        for (int j = 0; j < 8; j++) a[j] += wg * (float)v[j];
    }
    f16x8 o;
#pragma unroll
    for (int j = 0; j < 8; j++) o[j] = (_Float16)a[j];
    ((f16x8*)out)[(size_t)node * 64 + lane] = o;
}

// ------------- 256x128 GEMM, BK=32, 8 waves x (64x64), 2 blocks/CU -------------------
// C[M,N] = A[M,K] @ W[N,K]^T + bias. N%128==0, K%32==0.
// R11 lesson: occupancy doubled (43%) but bm-fast XCD map re-streamed A x8
// (FETCH 1.65GB) -> HBM-bound. R12 fix: bn-FAST within XCD chunk (R3 orientation):
// per XCD, B is L3-resident and A streams once -> FETCH ~0.35GB, so the doubled
// occupancy (4 waves/SIMD, 2 blocks/CU) can actually fill stall slots (m114).
// Per tile t (buf t%3): stage {B,Alo,Ahi}(t+2) -> buf (t+2)%3 (WAR-safe: that buf
// was read in tile t-1, drained before its end barrier); 8 ds_reads; 16 MFMA;
// vmcnt(3) (drains t+1, keeps t+2's 3 in flight — never 0); 1 barrier.
// Swizzle (64B rows, verified conflicts=0 in R8/R11): read byte ^= (((row>>1)&3)<<4);
// staging source pre-swizzled q ^= (((q>>6)&3)<<3).
#define FENCE() asm volatile("" ::: "memory")
#define BAR()   do { FENCE(); __builtin_amdgcn_s_barrier(); FENCE(); } while (0)
#define WAITV3() asm volatile("s_waitcnt vmcnt(3)" ::: "memory")
#define WAITV0() asm volatile("s_waitcnt vmcnt(0)" ::: "memory")
#define GLD(src, dst) __builtin_amdgcn_global_load_lds( \
    (const __attribute__((address_space(1))) void*)(src), \
    (__attribute__((address_space(3))) void*)(dst), 16, 0, 0)
#define LDF(base, row) \
    (*(const f16x8*)((base) + ((((row) * 64 + fqo)) ^ ((((row) >> 1) & 3) << 4))))
#define MM(mi, nj, A_, B_) \
    acc[mi][nj] = __builtin_amdgcn_mfma_f32_16x16x32_f16(A_, B_, acc[mi][nj], 0, 0, 0)

template <int ACT, typename OUT_T>
__global__ __launch_bounds__(512, 4) void k_gemm8(const half_t* __restrict__ A,
                                                  const half_t* __restrict__ W,
                                                  const float* __restrict__ bias,
                                                  OUT_T* __restrict__ C,
                                                  int M, int N, int K) {
    __shared__ half_t sm[36864];   // 3 bufs x (A 8192 + B 4096 halves) = 72KB
    // XCD-chunked bijective remap, bn-FAST within chunk (R3 orientation): each
    // XCD sweeps all bn panels per bm row -> B L3-resident, A streamed ~once.
    const int gx = gridDim.x;            // N/128
    const int nwg = gx * gridDim.y;
    int b = blockIdx.y * gx + blockIdx.x;
    int w8 = ((nwg & 7) == 0) ? (b & 7) * (nwg >> 3) + (b >> 3) : b;
    const int bn = (w8 % gx) * 128;
    const int bm = (w8 / gx) * 256;

    const int t = threadIdx.x;
    const int w = t >> 6, lane = t & 63;
    const int fr = lane & 15, fq = lane >> 4;
    const int fqo = fq * 16;
    const int wm = (w >> 1) * 64, wn = (w & 1) * 64;
    const int NT = K >> 5;

    // staging: per-thread source index q in [0,4096) pre-swizzled (R8 involution)
    int q = w * 512 + lane * 8;
    int s = q ^ (((q >> 6) & 3) << 3);
    int r = s >> 5, c = s & 31;
    const half_t* gAlo = A + (size_t)min(bm + r, M - 1) * K + c;
    const half_t* gAhi = A + (size_t)min(bm + 128 + r, M - 1) * K + c;
    const half_t* gB   = W + (size_t)(bn + r) * K + c;
    const int dst0 = w * 512;

#define STAGE(b3, kt) do {                                                     \
    GLD(gB   + (size_t)(kt) * 32, &sm[(b3) * 12288 + 8192 + dst0]);            \
    GLD(gAlo + (size_t)(kt) * 32, &sm[(b3) * 12288 + dst0]);                   \
    GLD(gAhi + (size_t)(kt) * 32, &sm[(b3) * 12288 + 4096 + dst0]);            \
} while (0)

    f32x4 acc[4][4] = {};

    // prologue: tiles 0,1 -> bufs 0,1 (6 loads); vmcnt(3) lands tile0, keeps tile1.
    STAGE(0, 0);
    STAGE(1, (NT > 1) ? 1 : 0);
    WAITV3();
    BAR();

    for (int tt = 0; tt < NT; ++tt) {
        const int cur = tt % 3;
        const int s2 = (tt + 2) % 3;
        const int kt = (tt + 2 < NT) ? tt + 2 : NT - 1;
        const char* smA = (const char*)&sm[cur * 12288];
        const char* smB = smA + 16384;   // 8192 halves
        STAGE(s2, kt);
        f16x8 b0 = LDF(smB, wn + fr);
        f16x8 b1 = LDF(smB, wn + 16 + fr);
        f16x8 b2 = LDF(smB, wn + 32 + fr);
        f16x8 b3 = LDF(smB, wn + 48 + fr);
        __builtin_amdgcn_s_setprio(1);
#pragma unroll
        for (int mi = 0; mi < 4; mi++) {
            f16x8 a = LDF(smA, wm + mi * 16 + fr);
            MM(mi, 0, a, b0); MM(mi, 1, a, b1);
            MM(mi, 2, a, b2); MM(mi, 3, a, b3);
        }
        __builtin_amdgcn_s_setprio(0);
        WAITV3();   // drains tile tt+1's 3 loads; keeps (tt+2)'s 3 in flight
        BAR();
    }
    WAITV0();
#undef STAGE

    // epilogue: D frag mapping col = lane&15, row = (lane>>4)*4 + r
    const int col0 = bn + wn + fr;
#pragma unroll
    for (int mi = 0; mi < 4; mi++) {
        int rb = bm + wm + mi * 16 + fq * 4;
#pragma unroll
        for (int nj = 0; nj < 4; nj++) {
            int col = col0 + nj * 16;
            float bv = bias[col];
#pragma unroll
            for (int rr = 0; rr < 4; rr++) {
                int row = rb + rr;
                if (row < M) {
                    float v = acc[mi][nj][rr] + bv;
                    if (ACT == 1) v = fmaxf(v, 0.f);
                    if (ACT == 2) v = 0.5f * v * (1.f + erff(v * 0.70710678118f));
                    C[(size_t)row * N + col] = (OUT_T)v;
                }
            }
        }
    }
}

// ---------------- launch ----------------
extern "C" void kernel_launch(void* const* d_in, const int* in_sizes, int n_in,
                              void* d_out, int out_size, void* d_ws, size_t ws_size,
                              hipStream_t stream) {
    const float* x     = (const float*)d_in[0];
    const int*   eidx  = (const int*)d_in[1];
    const float* gn_w  = (const float*)d_in[2];
    const float* gn_b  = (const float*)d_in[3];
    const float* gn_ms = (const float*)d_in[4];
    const float* w1    = (const float*)d_in[5];
    const float* b1    = (const float*)d_in[6];
    const float* w2    = (const float*)d_in[7];
    const float* b2    = (const float*)d_in[8];
    const float* p1    = (const float*)d_in[9];
    const float* pb1   = (const float*)d_in[10];
    const float* p2    = (const float*)d_in[11];
    const float* pb2   = (const float*)d_in[12];

    const int Nn = in_sizes[0] / D_PROT;   // 50000
    const int E  = in_sizes[1] / 2;        // 400000
    const int M  = Nn;

    char* ws = (char*)d_ws;
    size_t off = 0;
    auto alloc = [&](size_t bytes) {
        void* p = ws + off;
        off += (bytes + 255) & ~(size_t)255;
        return p;
    };
    half_t* w1h    = (half_t*)alloc((size_t)D_PROT * D_PROT * 2);
    half_t* w2h    = (half_t*)alloc((size_t)D_PROT * D_PROT * 2);
    half_t* p1h    = (half_t*)alloc((size_t)D_TEXT * D_PROT * 2);
    half_t* p2h    = (half_t*)alloc((size_t)D_TEXT * D_TEXT * 2);
    int*    deg    = (int*)alloc((size_t)Nn * 4);
    float*  dinv   = (float*)alloc((size_t)Nn * 4);
    int*    rowptr = (int*)alloc((size_t)(Nn + 1) * 4);
    int*    fillc  = (int*)alloc((size_t)Nn * 4);
    int*    bsum   = (int*)alloc(4096);
    int*    boff   = (int*)alloc(4096);
    int*    colidx = (int*)alloc((size_t)E * 4);
    float*  sums   = (float*)alloc(D_PROT * 4);
    float*  sumsq  = (float*)alloc(D_PROT * 4);
    float*  gnab   = (float*)alloc(2 * D_PROT * 4);
    half_t* buf1   = (half_t*)alloc((size_t)Nn * D_PROT * 2);
    half_t* buf2   = (half_t*)alloc((size_t)Nn * D_PROT * 2);
    half_t* big    = (half_t*)alloc((size_t)Nn * D_TEXT * 2);

    const int* esrc = eidx;
    const int* edst = eidx + E;

    hipMemsetAsync(deg, 0, (size_t)Nn * 4, stream);
    hipMemsetAsync(fillc, 0, (size_t)Nn * 4, stream);
    hipMemsetAsync(rowptr, 0, (size_t)(Nn + 1) * 4, stream);
    hipMemsetAsync(sums, 0, D_PROT * 4, stream);
    hipMemsetAsync(sumsq, 0, D_PROT * 4, stream);

    k_cvt4<<<(D_PROT * D_PROT / 4 + 255) / 256, 256, 0, stream>>>(w1, w1h, D_PROT * D_PROT / 4);
    k_cvt4<<<(D_PROT * D_PROT / 4 + 255) / 256, 256, 0, stream>>>(w2, w2h, D_PROT * D_PROT / 4);
    k_cvt4<<<(D_TEXT * D_PROT / 4 + 255) / 256, 256, 0, stream>>>(p1, p1h, D_TEXT * D_PROT / 4);
    k_cvt4<<<(D_TEXT * D_TEXT / 4 + 255) / 256, 256, 0, stream>>>(p2, p2h, D_TEXT * D_TEXT / 4);

    int eb = (E + 255) / 256;
    int nb = (Nn + 255) / 256;
    k_deg<<<eb, 256, 0, stream>>>(edst, E, deg);
    k_dinv<<<nb, 256, 0, stream>>>(deg, dinv, Nn);
    k_blocksum<<<nb, 256, 0, stream>>>(deg, bsum, Nn);
    k_scan_bsum<<<1, 256, 0, stream>>>(bsum, boff, nb);
    k_scan_final<<<nb, 256, 0, stream>>>(deg, boff, rowptr, Nn);
    k_fill<<<eb, 256, 0, stream>>>(esrc, edst, E, rowptr, fillc, colidx);

    k_gnreduce<<<256, 256, 0, stream>>>(x, sums, sumsq, Nn);
    k_gnfinal<<<2, 256, 0, stream>>>(sums, sumsq, gn_w, gn_b, gn_ms, gnab, 1.0f / (float)Nn);
    int n4 = Nn * D_PROT / 4;
    k_gnnorm<<<(n4 + 255) / 256, 256, 0, stream>>>(x, gnab, buf1, n4);

    const int mt256 = (M + 255) / 256;
    const int aggb = (Nn + 3) / 4;

    // conv1: agg -> gemm+relu
    k_agg<<<aggb, 256, 0, stream>>>(buf1, buf2, rowptr, colidx, dinv, Nn);
    {
        dim3 g(D_PROT / 128, mt256);
        k_gemm8<1, half_t><<<g, 512, 0, stream>>>(buf2, w1h, b1, buf1, M, D_PROT, D_PROT);
    }
    // conv2
    k_agg<<<aggb, 256, 0, stream>>>(buf1, buf2, rowptr, colidx, dinv, Nn);
    {
        dim3 g(D_PROT / 128, mt256);
        k_gemm8<1, half_t><<<g, 512, 0, stream>>>(buf2, w2h, b2, buf1, M, D_PROT, D_PROT);
    }
    // proj1 + gelu
    {
        dim3 g(D_TEXT / 128, mt256);
        k_gemm8<2, half_t><<<g, 512, 0, stream>>>(buf1, p1h, pb1, big, M, D_TEXT, D_PROT);
    }
    // proj2 -> fp32 out
    {
        dim3 g(D_TEXT / 128, mt256);
        k_gemm8<0, float><<<g, 512, 0, stream>>>(big, p2h, pb2, (float*)d_out, M, D_TEXT, D_TEXT);
    }
}

// Round 13
// 1189.432 us; speedup vs baseline: 1.0840x; 1.0027x over previous
//
#include <hip/hip_runtime.h>
#include <math.h>

typedef _Float16 half_t;
typedef _Float16 f16x4 __attribute__((ext_vector_type(4)));
typedef _Float16 f16x8 __attribute__((ext_vector_type(8)));
typedef float f32x4 __attribute__((ext_vector_type(4)));

#define D_PROT 512
#define D_TEXT 2048

// ---------------- utility: fp32 -> fp16 convert (vector x4) ----------------
__global__ void k_cvt4(const float* __restrict__ s, half_t* __restrict__ d, int n4) {
    int i = blockIdx.x * 256 + threadIdx.x;
    if (i < n4) {
        float4 v = ((const float4*)s)[i];
        f16x4 o;
        o.x = (_Float16)v.x; o.y = (_Float16)v.y;
        o.z = (_Float16)v.z; o.w = (_Float16)v.w;
        ((f16x4*)d)[i] = o;
    }
}

// ---------------- degree histogram ----------------
__global__ void k_deg(const int* __restrict__ dst, int E, int* __restrict__ deg) {
    int i = blockIdx.x * 256 + threadIdx.x;
    if (i < E) atomicAdd(&deg[dst[i]], 1);
}

__global__ void k_dinv(const int* __restrict__ deg, float* __restrict__ dinv, int n) {
    int i = blockIdx.x * 256 + threadIdx.x;
    if (i < n) dinv[i] = rsqrtf((float)deg[i] + 1.0f);
}

// ---------------- prefix sum ----------------
__global__ void k_blocksum(const int* __restrict__ deg, int* __restrict__ bsum, int n) {
    __shared__ int sd[256];
    int i = blockIdx.x * 256 + threadIdx.x;
    sd[threadIdx.x] = (i < n) ? deg[i] : 0;
    __syncthreads();
    for (int s = 128; s > 0; s >>= 1) {
        if (threadIdx.x < s) sd[threadIdx.x] += sd[threadIdx.x + s];
        __syncthreads();
    }
    if (threadIdx.x == 0) bsum[blockIdx.x] = sd[0];
}

__global__ void k_scan_bsum(const int* __restrict__ bsum, int* __restrict__ boff, int nb) {
    __shared__ int sd[1024];
    int t = threadIdx.x;  // 256
    for (int i = t; i < 1024; i += 256) sd[i] = (i < nb) ? bsum[i] : 0;
    __syncthreads();
    for (int s = 1; s < 1024; s <<= 1) {
        int vals[4];
#pragma unroll
        for (int k = 0; k < 4; k++) {
            int i = t + k * 256;
            vals[k] = (i >= s) ? sd[i - s] : 0;
        }
        __syncthreads();
#pragma unroll
        for (int k = 0; k < 4; k++) sd[t + k * 256] += vals[k];
        __syncthreads();
    }
    for (int i = t; i < nb; i += 256) boff[i] = (i > 0) ? sd[i - 1] : 0;
}

__global__ void k_scan_final(const int* __restrict__ deg, const int* __restrict__ boff,
                             int* __restrict__ rowptr, int n) {
    __shared__ int sd[256];
    int i = blockIdx.x * 256 + threadIdx.x;
    int v = (i < n) ? deg[i] : 0;
    sd[threadIdx.x] = v;
    __syncthreads();
    for (int s = 1; s < 256; s <<= 1) {
        int t2 = (threadIdx.x >= s) ? sd[threadIdx.x - s] : 0;
        __syncthreads();
        sd[threadIdx.x] += t2;
        __syncthreads();
    }
    if (i < n) rowptr[i + 1] = boff[blockIdx.x] + sd[threadIdx.x];
}

// ---------------- CSR fill (atomic append) ----------------
__global__ void k_fill(const int* __restrict__ src, const int* __restrict__ dst, int E,
                       const int* __restrict__ rowptr, int* __restrict__ fill,
                       int* __restrict__ colidx) {
    int i = blockIdx.x * 256 + threadIdx.x;
    if (i < E) {
        int d = dst[i];
        int pos = atomicAdd(&fill[d], 1);
        colidx[rowptr[d] + pos] = src[i];
    }
}

// ---------------- GraphNorm ----------------
__global__ void k_gnreduce(const float* __restrict__ x, float* __restrict__ sums,
                           float* __restrict__ sumsq, int Nn) {
    int t = threadIdx.x;
    int c = t * 2;
    float s0 = 0, s1 = 0, q0 = 0, q1 = 0;
    for (int r = blockIdx.x; r < Nn; r += gridDim.x) {
        float2 v = *(const float2*)(x + (size_t)r * D_PROT + c);
        s0 += v.x; s1 += v.y; q0 += v.x * v.x; q1 += v.y * v.y;
    }
    atomicAdd(&sums[c], s0);  atomicAdd(&sums[c + 1], s1);
    atomicAdd(&sumsq[c], q0); atomicAdd(&sumsq[c + 1], q1);
}

__global__ void k_gnfinal(const float* __restrict__ sums, const float* __restrict__ sumsq,
                          const float* __restrict__ w, const float* __restrict__ b,
                          const float* __restrict__ ms, float* __restrict__ ab, float invN) {
    int d = blockIdx.x * 256 + threadIdx.x;
    if (d < D_PROT) {
        float mean = sums[d] * invN;
        float m2 = sumsq[d] * invN;
        float mm = mean * ms[d];
        float var = m2 - 2.f * mm * mean + mm * mm;
        float rstd = rsqrtf(var + 1e-5f);
        float a = rstd * w[d];
        ab[d] = a;
        ab[D_PROT + d] = b[d] - mm * a;
    }
}

__global__ void k_gnnorm(const float* __restrict__ x, const float* __restrict__ ab,
                         half_t* __restrict__ h, int n4) {
    int i = blockIdx.x * 256 + threadIdx.x;
    if (i < n4) {
        size_t idx = (size_t)i * 4;
        float4 v = *(const float4*)(x + idx);
        int d = (int)(idx & (D_PROT - 1));
        const float* a = ab;
        const float* bb = ab + D_PROT;
        f16x4 o;
        o.x = (_Float16)(v.x * a[d]     + bb[d]);
        o.y = (_Float16)(v.y * a[d + 1] + bb[d + 1]);
        o.z = (_Float16)(v.z * a[d + 2] + bb[d + 2]);
        o.w = (_Float16)(v.w * a[d + 3] + bb[d + 3]);
        *(f16x4*)(h + idx) = o;
    }
}

// ---------------- SGConv aggregation: wave-per-node, 16B/lane, 4-deep ----------------
__global__ void k_agg(const half_t* __restrict__ h, half_t* __restrict__ out,
                      const int* __restrict__ rowptr, const int* __restrict__ colidx,
                      const float* __restrict__ dinv, int Nn) {
    int wid = (blockIdx.x << 2) + (threadIdx.x >> 6);
    if (wid >= Nn) return;
    int lane = threadIdx.x & 63;
    int node = wid;
    float di = dinv[node];
    int beg = rowptr[node], end = rowptr[node + 1];
    const f16x8* hp = (const f16x8*)h;          // row stride = 512/8 = 64
    f16x8 sv = hp[(size_t)node * 64 + lane];
    float dii = di * di;
    float a[8];
#pragma unroll
    for (int j = 0; j < 8; j++) a[j] = (float)sv[j] * dii;
    int e = beg;
    for (; e + 4 <= end; e += 4) {
        int s0 = colidx[e],     s1 = colidx[e + 1];
        int s2 = colidx[e + 2], s3 = colidx[e + 3];
        float w0 = dinv[s0] * di, w1 = dinv[s1] * di;
        float w2 = dinv[s2] * di, w3 = dinv[s3] * di;
        f16x8 v0 = hp[(size_t)s0 * 64 + lane];
        f16x8 v1 = hp[(size_t)s1 * 64 + lane];
        f16x8 v2 = hp[(size_t)s2 * 64 + lane];
        f16x8 v3 = hp[(size_t)s3 * 64 + lane];
#pragma unroll
        for (int j = 0; j < 8; j++)
            a[j] += w0 * (float)v0[j] + w1 * (float)v1[j]
                  + w2 * (float)v2[j] + w3 * (float)v3[j];
    }
    for (; e < end; ++e) {
        int s = colidx[e];
        float wg = dinv[s] * di;
        f16x8 v = hp[(size_t)s * 64 + lane];
#pragma unroll
        for (int j = 0; j < 8; j++) a[j] += wg * (float)v[j];
    }
    f16x8 o;
#pragma unroll
    for (int j = 0; j < 8; j++) o[j] = (_Float16)a[j];
    ((f16x8*)out)[(size_t)node * 64 + lane] = o;
}

// ------------- 256x128 GEMM, BK=32, 8 waves x (64x64), 2 blocks/CU -------------------
// C[M,N] = A[M,K] @ W[N,K]^T + bias. N%128==0, K%32==0.
// R11 lesson: occupancy doubled (43%) but bm-fast XCD map re-streamed A x8
// (FETCH 1.65GB) -> HBM-bound. R12 fix: bn-FAST within XCD chunk (R3 orientation):
// per XCD, B is L3-resident and A streams once -> FETCH ~0.35GB, so the doubled
// occupancy (4 waves/SIMD, 2 blocks/CU) can actually fill stall slots (m114).
// Per tile t (buf t%3): stage {B,Alo,Ahi}(t+2) -> buf (t+2)%3 (WAR-safe: that buf
// was read in tile t-1, drained before its end barrier); 8 ds_reads; 16 MFMA;
// vmcnt(3) (drains t+1, keeps t+2's 3 in flight — never 0); 1 barrier.
// Swizzle (64B rows, verified conflicts=0 in R8/R11): read byte ^= (((row>>1)&3)<<4);
// staging source pre-swizzled q ^= (((q>>6)&3)<<3).
#define FENCE() asm volatile("" ::: "memory")
#define BAR()   do { FENCE(); __builtin_amdgcn_s_barrier(); FENCE(); } while (0)
#define WAITV3() asm volatile("s_waitcnt vmcnt(3)" ::: "memory")
#define WAITV0() asm volatile("s_waitcnt vmcnt(0)" ::: "memory")
#define GLD(src, dst) __builtin_amdgcn_global_load_lds( \
    (const __attribute__((address_space(1))) void*)(src), \
    (__attribute__((address_space(3))) void*)(dst), 16, 0, 0)
#define LDF(base, row) \
    (*(const f16x8*)((base) + ((((row) * 64 + fqo)) ^ ((((row) >> 1) & 3) << 4))))
#define MM(mi, nj, A_, B_) \
    acc[mi][nj] = __builtin_amdgcn_mfma_f32_16x16x32_f16(A_, B_, acc[mi][nj], 0, 0, 0)

template <int ACT, typename OUT_T>
__global__ __launch_bounds__(512, 4) void k_gemm8(const half_t* __restrict__ A,
                                                  const half_t* __restrict__ W,
                                                  const float* __restrict__ bias,
                                                  OUT_T* __restrict__ C,
                                                  int M, int N, int K) {
    __shared__ half_t sm[36864];   // 3 bufs x (A 8192 + B 4096 halves) = 72KB
    // XCD-chunked bijective remap, bn-FAST within chunk (R3 orientation): each
    // XCD sweeps all bn panels per bm row -> B L3-resident, A streamed ~once.
    const int gx = gridDim.x;            // N/128
    const int nwg = gx * gridDim.y;
    int b = blockIdx.y * gx + blockIdx.x;
    int w8 = ((nwg & 7) == 0) ? (b & 7) * (nwg >> 3) + (b >> 3) : b;
    const int bn = (w8 % gx) * 128;
    const int bm = (w8 / gx) * 256;

    const int t = threadIdx.x;
    const int w = t >> 6, lane = t & 63;
    const int fr = lane & 15, fq = lane >> 4;
    const int fqo = fq * 16;
    const int wm = (w >> 1) * 64, wn = (w & 1) * 64;
    const int NT = K >> 5;

    // staging: per-thread source index q in [0,4096) pre-swizzled (R8 involution)
    int q = w * 512 + lane * 8;
    int s = q ^ (((q >> 6) & 3) << 3);
    int r = s >> 5, c = s & 31;
    const half_t* gAlo = A + (size_t)min(bm + r, M - 1) * K + c;
    const half_t* gAhi = A + (size_t)min(bm + 128 + r, M - 1) * K + c;
    const half_t* gB   = W + (size_t)(bn + r) * K + c;
    const int dst0 = w * 512;

#define STAGE(b3, kt) do {                                                     \
    GLD(gB   + (size_t)(kt) * 32, &sm[(b3) * 12288 + 8192 + dst0]);            \
    GLD(gAlo + (size_t)(kt) * 32, &sm[(b3) * 12288 + dst0]);                   \
    GLD(gAhi + (size_t)(kt) * 32, &sm[(b3) * 12288 + 4096 + dst0]);            \
} while (0)

    f32x4 acc[4][4] = {};

    // prologue: tiles 0,1 -> bufs 0,1 (6 loads); vmcnt(3) lands tile0, keeps tile1.
    STAGE(0, 0);
    STAGE(1, (NT > 1) ? 1 : 0);
    WAITV3();
    BAR();

    for (int tt = 0; tt < NT; ++tt) {
        const int cur = tt % 3;
        const int s2 = (tt + 2) % 3;
        const int kt = (tt + 2 < NT) ? tt + 2 : NT - 1;
        const char* smA = (const char*)&sm[cur * 12288];
        const char* smB = smA + 16384;   // 8192 halves
        STAGE(s2, kt);
        f16x8 b0 = LDF(smB, wn + fr);
        f16x8 b1 = LDF(smB, wn + 16 + fr);
        f16x8 b2 = LDF(smB, wn + 32 + fr);
        f16x8 b3 = LDF(smB, wn + 48 + fr);
        __builtin_amdgcn_s_setprio(1);
#pragma unroll
        for (int mi = 0; mi < 4; mi++) {
            f16x8 a = LDF(smA, wm + mi * 16 + fr);
            MM(mi, 0, a, b0); MM(mi, 1, a, b1);
            MM(mi, 2, a, b2); MM(mi, 3, a, b3);
        }
        __builtin_amdgcn_s_setprio(0);
        WAITV3();   // drains tile tt+1's 3 loads; keeps (tt+2)'s 3 in flight
        BAR();
    }
    WAITV0();
#undef STAGE

    // epilogue: D frag mapping col = lane&15, row = (lane>>4)*4 + r
    const int col0 = bn + wn + fr;
#pragma unroll
    for (int mi = 0; mi < 4; mi++) {
        int rb = bm + wm + mi * 16 + fq * 4;
#pragma unroll
        for (int nj = 0; nj < 4; nj++) {
            int col = col0 + nj * 16;
            float bv = bias[col];
#pragma unroll
            for (int rr = 0; rr < 4; rr++) {
                int row = rb + rr;
                if (row < M) {
                    float v = acc[mi][nj][rr] + bv;
                    if (ACT == 1) v = fmaxf(v, 0.f);
                    if (ACT == 2) v = 0.5f * v * (1.f + erff(v * 0.70710678118f));
                    C[(size_t)row * N + col] = (OUT_T)v;
                }
            }
        }
    }
}

// ---------------- launch ----------------
extern "C" void kernel_launch(void* const* d_in, const int* in_sizes, int n_in,
                              void* d_out, int out_size, void* d_ws, size_t ws_size,
                              hipStream_t stream) {
    const float* x     = (const float*)d_in[0];
    const int*   eidx  = (const int*)d_in[1];
    const float* gn_w  = (const float*)d_in[2];
    const float* gn_b  = (const float*)d_in[3];
    const float* gn_ms = (const float*)d_in[4];
    const float* w1    = (const float*)d_in[5];
    const float* b1    = (const float*)d_in[6];
    const float* w2    = (const float*)d_in[7];
    const float* b2    = (const float*)d_in[8];
    const float* p1    = (const float*)d_in[9];
    const float* pb1   = (const float*)d_in[10];
    const float* p2    = (const float*)d_in[11];
    const float* pb2   = (const float*)d_in[12];

    const int Nn = in_sizes[0] / D_PROT;   // 50000
    const int E  = in_sizes[1] / 2;        // 400000
    const int M  = Nn;

    char* ws = (char*)d_ws;
    size_t off = 0;
    auto alloc = [&](size_t bytes) {
        void* p = ws + off;
        off += (bytes + 255) & ~(size_t)255;
        return p;
    };
    half_t* w1h    = (half_t*)alloc((size_t)D_PROT * D_PROT * 2);
    half_t* w2h    = (half_t*)alloc((size_t)D_PROT * D_PROT * 2);
    half_t* p1h    = (half_t*)alloc((size_t)D_TEXT * D_PROT * 2);
    half_t* p2h    = (half_t*)alloc((size_t)D_TEXT * D_TEXT * 2);
    int*    deg    = (int*)alloc((size_t)Nn * 4);
    float*  dinv   = (float*)alloc((size_t)Nn * 4);
    int*    rowptr = (int*)alloc((size_t)(Nn + 1) * 4);
    int*    fillc  = (int*)alloc((size_t)Nn * 4);
    int*    bsum   = (int*)alloc(4096);
    int*    boff   = (int*)alloc(4096);
    int*    colidx = (int*)alloc((size_t)E * 4);
    float*  sums   = (float*)alloc(D_PROT * 4);
    float*  sumsq  = (float*)alloc(D_PROT * 4);
    float*  gnab   = (float*)alloc(2 * D_PROT * 4);
    half_t* buf1   = (half_t*)alloc((size_t)Nn * D_PROT * 2);
    half_t* buf2   = (half_t*)alloc((size_t)Nn * D_PROT * 2);
    half_t* big    = (half_t*)alloc((size_t)Nn * D_TEXT * 2);

    const int* esrc = eidx;
    const int* edst = eidx + E;

    hipMemsetAsync(deg, 0, (size_t)Nn * 4, stream);
    hipMemsetAsync(fillc, 0, (size_t)Nn * 4, stream);
    hipMemsetAsync(rowptr, 0, (size_t)(Nn + 1) * 4, stream);
    hipMemsetAsync(sums, 0, D_PROT * 4, stream);
    hipMemsetAsync(sumsq, 0, D_PROT * 4, stream);

    k_cvt4<<<(D_PROT * D_PROT / 4 + 255) / 256, 256, 0, stream>>>(w1, w1h, D_PROT * D_PROT / 4);
    k_cvt4<<<(D_PROT * D_PROT / 4 + 255) / 256, 256, 0, stream>>>(w2, w2h, D_PROT * D_PROT / 4);
    k_cvt4<<<(D_TEXT * D_PROT / 4 + 255) / 256, 256, 0, stream>>>(p1, p1h, D_TEXT * D_PROT / 4);
    k_cvt4<<<(D_TEXT * D_TEXT / 4 + 255) / 256, 256, 0, stream>>>(p2, p2h, D_TEXT * D_TEXT / 4);

    int eb = (E + 255) / 256;
    int nb = (Nn + 255) / 256;
    k_deg<<<eb, 256, 0, stream>>>(edst, E, deg);
    k_dinv<<<nb, 256, 0, stream>>>(deg, dinv, Nn);
    k_blocksum<<<nb, 256, 0, stream>>>(deg, bsum, Nn);
    k_scan_bsum<<<1, 256, 0, stream>>>(bsum, boff, nb);
    k_scan_final<<<nb, 256, 0, stream>>>(deg, boff, rowptr, Nn);
    k_fill<<<eb, 256, 0, stream>>>(esrc, edst, E, rowptr, fillc, colidx);

    k_gnreduce<<<256, 256, 0, stream>>>(x, sums, sumsq, Nn);
    k_gnfinal<<<2, 256, 0, stream>>>(sums, sumsq, gn_w, gn_b, gn_ms, gnab, 1.0f / (float)Nn);
    int n4 = Nn * D_PROT / 4;
    k_gnnorm<<<(n4 + 255) / 256, 256, 0, stream>>>(x, gnab, buf1, n4);

    const int mt256 = (M + 255) / 256;
    const int aggb = (Nn + 3) / 4;

    // conv1: agg -> gemm+relu
    k_agg<<<aggb, 256, 0, stream>>>(buf1, buf2, rowptr, colidx, dinv, Nn);
    {
        dim3 g(D_PROT / 128, mt256);
        k_gemm8<1, half_t><<<g, 512, 0, stream>>>(buf2, w1h, b1, buf1, M, D_PROT, D_PROT);
    }
    // conv2
    k_agg<<<aggb, 256, 0, stream>>>(buf1, buf2, rowptr, colidx, dinv, Nn);
    {
        dim3 g(D_PROT / 128, mt256);
        k_gemm8<1, half_t><<<g, 512, 0, stream>>>(buf2, w2h, b2, buf1, M, D_PROT, D_PROT);
    }
    // proj1 + gelu
    {
        dim3 g(D_TEXT / 128, mt256);
        k_gemm8<2, half_t><<<g, 512, 0, stream>>>(buf1, p1h, pb1, big, M, D_TEXT, D_PROT);
    }
    // proj2 -> fp32 out
    {
        dim3 g(D_TEXT / 128, mt256);
        k_gemm8<0, float><<<g, 512, 0, stream>>>(big, p2h, pb2, (float*)d_out, M, D_TEXT, D_TEXT);
    }
}

// Round 14
// 1095.981 us; speedup vs baseline: 1.1765x; 1.0853x over previous
//
#include <hip/hip_runtime.h>
#include <math.h>

typedef _Float16 half_t;
typedef _Float16 f16x4 __attribute__((ext_vector_type(4)));
typedef _Float16 f16x8 __attribute__((ext_vector_type(8)));
typedef float f32x4 __attribute__((ext_vector_type(4)));

#define D_PROT 512
#define D_TEXT 2048

// ---------------- utility: fp32 -> fp16 convert (vector x4) ----------------
__global__ void k_cvt4(const float* __restrict__ s, half_t* __restrict__ d, int n4) {
    int i = blockIdx.x * 256 + threadIdx.x;
    if (i < n4) {
        float4 v = ((const float4*)s)[i];
        f16x4 o;
        o.x = (_Float16)v.x; o.y = (_Float16)v.y;
        o.z = (_Float16)v.z; o.w = (_Float16)v.w;
        ((f16x4*)d)[i] = o;
    }
}

// ---------------- degree histogram ----------------
__global__ void k_deg(const int* __restrict__ dst, int E, int* __restrict__ deg) {
    int i = blockIdx.x * 256 + threadIdx.x;
    if (i < E) atomicAdd(&deg[dst[i]], 1);
}

__global__ void k_dinv(const int* __restrict__ deg, float* __restrict__ dinv, int n) {
    int i = blockIdx.x * 256 + threadIdx.x;
    if (i < n) dinv[i] = rsqrtf((float)deg[i] + 1.0f);
}

// ---------------- prefix sum ----------------
__global__ void k_blocksum(const int* __restrict__ deg, int* __restrict__ bsum, int n) {
    __shared__ int sd[256];
    int i = blockIdx.x * 256 + threadIdx.x;
    sd[threadIdx.x] = (i < n) ? deg[i] : 0;
    __syncthreads();
    for (int s = 128; s > 0; s >>= 1) {
        if (threadIdx.x < s) sd[threadIdx.x] += sd[threadIdx.x + s];
        __syncthreads();
    }
    if (threadIdx.x == 0) bsum[blockIdx.x] = sd[0];
}

__global__ void k_scan_bsum(const int* __restrict__ bsum, int* __restrict__ boff, int nb) {
    __shared__ int sd[1024];
    int t = threadIdx.x;  // 256
    for (int i = t; i < 1024; i += 256) sd[i] = (i < nb) ? bsum[i] : 0;
    __syncthreads();
    for (int s = 1; s < 1024; s <<= 1) {
        int vals[4];
#pragma unroll
        for (int k = 0; k < 4; k++) {
            int i = t + k * 256;
            vals[k] = (i >= s) ? sd[i - s] : 0;
        }
        __syncthreads();
#pragma unroll
        for (int k = 0; k < 4; k++) sd[t + k * 256] += vals[k];
        __syncthreads();
    }
    for (int i = t; i < nb; i += 256) boff[i] = (i > 0) ? sd[i - 1] : 0;
}

__global__ void k_scan_final(const int* __restrict__ deg, const int* __restrict__ boff,
                             int* __restrict__ rowptr, int n) {
    __shared__ int sd[256];
    int i = blockIdx.x * 256 + threadIdx.x;
    int v = (i < n) ? deg[i] : 0;
    sd[threadIdx.x] = v;
    __syncthreads();
    for (int s = 1; s < 256; s <<= 1) {
        int t2 = (threadIdx.x >= s) ? sd[threadIdx.x - s] : 0;
        __syncthreads();
        sd[threadIdx.x] += t2;
        __syncthreads();
    }
    if (i < n) rowptr[i + 1] = boff[blockIdx.x] + sd[threadIdx.x];
}

// ---------------- CSR fill (atomic append) ----------------
__global__ void k_fill(const int* __restrict__ src, const int* __restrict__ dst, int E,
                       const int* __restrict__ rowptr, int* __restrict__ fill,
                       int* __restrict__ colidx) {
    int i = blockIdx.x * 256 + threadIdx.x;
    if (i < E) {
        int d = dst[i];
        int pos = atomicAdd(&fill[d], 1);
        colidx[rowptr[d] + pos] = src[i];
    }
}

// ---------------- GraphNorm ----------------
__global__ void k_gnreduce(const float* __restrict__ x, float* __restrict__ sums,
                           float* __restrict__ sumsq, int Nn) {
    int t = threadIdx.x;
    int c = t * 2;
    float s0 = 0, s1 = 0, q0 = 0, q1 = 0;
    for (int r = blockIdx.x; r < Nn; r += gridDim.x) {
        float2 v = *(const float2*)(x + (size_t)r * D_PROT + c);
        s0 += v.x; s1 += v.y; q0 += v.x * v.x; q1 += v.y * v.y;
    }
    atomicAdd(&sums[c], s0);  atomicAdd(&sums[c + 1], s1);
    atomicAdd(&sumsq[c], q0); atomicAdd(&sumsq[c + 1], q1);
}

__global__ void k_gnfinal(const float* __restrict__ sums, const float* __restrict__ sumsq,
                          const float* __restrict__ w, const float* __restrict__ b,
                          const float* __restrict__ ms, float* __restrict__ ab, float invN) {
    int d = blockIdx.x * 256 + threadIdx.x;
    if (d < D_PROT) {
        float mean = sums[d] * invN;
        float m2 = sumsq[d] * invN;
        float mm = mean * ms[d];
        float var = m2 - 2.f * mm * mean + mm * mm;
        float rstd = rsqrtf(var + 1e-5f);
        float a = rstd * w[d];
        ab[d] = a;
        ab[D_PROT + d] = b[d] - mm * a;
    }
}

__global__ void k_gnnorm(const float* __restrict__ x, const float* __restrict__ ab,
                         half_t* __restrict__ h, int n4) {
    int i = blockIdx.x * 256 + threadIdx.x;
    if (i < n4) {
        size_t idx = (size_t)i * 4;
        float4 v = *(const float4*)(x + idx);
        int d = (int)(idx & (D_PROT - 1));
        const float* a = ab;
        const float* bb = ab + D_PROT;
        f16x4 o;
        o.x = (_Float16)(v.x * a[d]     + bb[d]);
        o.y = (_Float16)(v.y * a[d + 1] + bb[d + 1]);
        o.z = (_Float16)(v.z * a[d + 2] + bb[d + 2]);
        o.w = (_Float16)(v.w * a[d + 3] + bb[d + 3]);
        *(f16x4*)(h + idx) = o;
    }
}

// ---------------- SGConv aggregation: wave-per-node, 16B/lane, 4-deep ----------------
__global__ void k_agg(const half_t* __restrict__ h, half_t* __restrict__ out,
                      const int* __restrict__ rowptr, const int* __restrict__ colidx,
                      const float* __restrict__ dinv, int Nn) {
    int wid = (blockIdx.x << 2) + (threadIdx.x >> 6);
    if (wid >= Nn) return;
    int lane = threadIdx.x & 63;
    int node = wid;
    float di = dinv[node];
    int beg = rowptr[node], end = rowptr[node + 1];
    const f16x8* hp = (const f16x8*)h;          // row stride = 512/8 = 64
    f16x8 sv = hp[(size_t)node * 64 + lane];
    float dii = di * di;
    float a[8];
#pragma unroll
    for (int j = 0; j < 8; j++) a[j] = (float)sv[j] * dii;
    int e = beg;
    for (; e + 4 <= end; e += 4) {
        int s0 = colidx[e],     s1 = colidx[e + 1];
        int s2 = colidx[e + 2], s3 = colidx[e + 3];
        float w0 = dinv[s0] * di, w1 = dinv[s1] * di;
        float w2 = dinv[s2] * di, w3 = dinv[s3] * di;
        f16x8 v0 = hp[(size_t)s0 * 64 + lane];
        f16x8 v1 = hp[(size_t)s1 * 64 + lane];
        f16x8 v2 = hp[(size_t)s2 * 64 + lane];
        f16x8 v3 = hp[(size_t)s3 * 64 + lane];
#pragma unroll
        for (int j = 0; j < 8; j++)
            a[j] += w0 * (float)v0[j] + w1 * (float)v1[j]
                  + w2 * (float)v2[j] + w3 * (float)v3[j];
    }
    for (; e < end; ++e) {
        int s = colidx[e];
        float wg = dinv[s] * di;
        f16x8 v = hp[(size_t)s * 64 + lane];
#pragma unroll
        for (int j = 0; j < 8; j++) a[j] += wg * (float)v[j];
    }
    f16x8 o;
#pragma unroll
    for (int j = 0; j < 8; j++) o[j] = (_Float16)a[j];
    ((f16x8*)out)[(size_t)node * 64 + lane] = o;
}

// ---------------- shared GEMM helpers ----------------
#define FENCE() asm volatile("" ::: "memory")
#define BAR()   do { FENCE(); __builtin_amdgcn_s_barrier(); FENCE(); } while (0)
#define WAITV4() asm volatile("s_waitcnt vmcnt(4)" ::: "memory")
#define WAITV3() asm volatile("s_waitcnt vmcnt(3)" ::: "memory")
#define WAITV0() asm volatile("s_waitcnt vmcnt(0)" ::: "memory")
#define GLD(src, dst) __builtin_amdgcn_global_load_lds( \
    (const __attribute__((address_space(1))) void*)(src), \
    (__attribute__((address_space(3))) void*)(dst), 16, 0, 0)
#define MM(mi, nj, A_, B_) \
    acc[mi][nj] = __builtin_amdgcn_mfma_f32_16x16x32_f16(A_, B_, acc[mi][nj], 0, 0, 0)

// ============ KERNEL 1: 256^2, BK=64, 8 waves, 4-phase (best for K=2048 layer) =======
// R3/R10-verified: proj2 519us, MfmaUtil 36.5%, conflicts 0, FETCH 335MB.
#define LDF256(base, row, kk) \
    (*(const f16x8*)((base) + ((((row) * 128 + (kk) * 64 + fqo)) ^ (((row) & 7) << 4))))

template <int ACT, typename OUT_T>
__global__ __launch_bounds__(512, 2) void k_gemm256(const half_t* __restrict__ A,
                                                    const half_t* __restrict__ W,
                                                    const float* __restrict__ bias,
                                                    OUT_T* __restrict__ C,
                                                    int M, int N, int K) {
    __shared__ half_t sm[2][32768];
    const int gx = gridDim.x;
    const int nwg = gx * gridDim.y;
    int b = blockIdx.y * gx + blockIdx.x;
    int w8 = ((nwg & 7) == 0) ? (b & 7) * (nwg >> 3) + (b >> 3) : b;
    const int bn = (w8 % gx) * 256;
    const int bm = (w8 / gx) * 256;

    const int t = threadIdx.x;
    const int w = t >> 6, lane = t & 63;
    const int fr = lane & 15, fq = lane >> 4;
    const int fqo = fq * 16;
    const int wm = (w >> 2) * 128, wn = (w & 3) * 64;
    const int NT = K >> 6;

    int q0 = w * 512 + lane * 8;
    int q1 = 4096 + q0;
    int s0 = q0 ^ (((q0 >> 6) & 7) << 3);
    int s1 = q1 ^ (((q1 >> 6) & 7) << 3);
    int r0 = s0 >> 6, c0 = s0 & 63;
    int r1 = s1 >> 6, c1 = s1 & 63;
    const half_t* gAlo0 = A + (size_t)min(bm + r0, M - 1) * K + c0;
    const half_t* gAlo1 = A + (size_t)min(bm + r1, M - 1) * K + c1;
    const half_t* gAhi0 = A + (size_t)min(bm + 128 + r0, M - 1) * K + c0;
    const half_t* gAhi1 = A + (size_t)min(bm + 128 + r1, M - 1) * K + c1;
    const half_t* gBlo0 = W + (size_t)(bn + r0) * K + c0;
    const half_t* gBlo1 = W + (size_t)(bn + r1) * K + c1;
    const half_t* gBhi0 = W + (size_t)(bn + 128 + r0) * K + c0;
    const half_t* gBhi1 = W + (size_t)(bn + 128 + r1) * K + c1;
    const int dst0 = w * 512;

    f32x4 acc[8][4] = {};

    GLD(gAlo0, &sm[0][dst0]);          GLD(gAlo1, &sm[0][4096 + dst0]);
    GLD(gAhi0, &sm[0][8192 + dst0]);   GLD(gAhi1, &sm[0][12288 + dst0]);
    GLD(gBlo0, &sm[0][16384 + dst0]);  GLD(gBlo1, &sm[0][20480 + dst0]);
    GLD(gBhi0, &sm[0][24576 + dst0]);  GLD(gBhi1, &sm[0][28672 + dst0]);
    GLD(gBlo0 + 64, &sm[1][16384 + dst0]);  GLD(gBlo1 + 64, &sm[1][20480 + dst0]);
    GLD(gBhi0 + 64, &sm[1][24576 + dst0]);  GLD(gBhi1 + 64, &sm[1][28672 + dst0]);
    WAITV4();
    BAR();

#define TILE(cur, nxt, ktA, ktB) do {                                          \
    const char* smA = (const char*)&sm[cur][0];                                 \
    const char* smB = (const char*)&sm[cur][16384];                             \
    f16x8 b00 = LDF256(smB, wn + fr, 0),      b01 = LDF256(smB, wn + fr, 1);    \
    f16x8 b10 = LDF256(smB, wn + 16 + fr, 0), b11 = LDF256(smB, wn + 16 + fr, 1); \
    f16x8 b20 = LDF256(smB, wn + 32 + fr, 0), b21 = LDF256(smB, wn + 32 + fr, 1); \
    f16x8 b30 = LDF256(smB, wn + 48 + fr, 0), b31 = LDF256(smB, wn + 48 + fr, 1); \
    f16x8 a00 = LDF256(smA, wm + fr, 0),      a01 = LDF256(smA, wm + fr, 1);    \
    f16x8 a10 = LDF256(smA, wm + 16 + fr, 0), a11 = LDF256(smA, wm + 16 + fr, 1); \
    GLD(gAlo0 + (size_t)(ktA) * 64, &sm[nxt][dst0]);                            \
    GLD(gAlo1 + (size_t)(ktA) * 64, &sm[nxt][4096 + dst0]);                     \
    GLD(gAhi0 + (size_t)(ktA) * 64, &sm[nxt][8192 + dst0]);                     \
    GLD(gAhi1 + (size_t)(ktA) * 64, &sm[nxt][12288 + dst0]);                    \
    BAR();                                                                      \
    __builtin_amdgcn_s_setprio(1);                                              \
    MM(0, 0, a00, b00); MM(0, 1, a00, b10); MM(0, 2, a00, b20); MM(0, 3, a00, b30); \
    MM(0, 0, a01, b01); MM(0, 1, a01, b11); MM(0, 2, a01, b21); MM(0, 3, a01, b31); \
    MM(1, 0, a10, b00); MM(1, 1, a10, b10); MM(1, 2, a10, b20); MM(1, 3, a10, b30); \
    MM(1, 0, a11, b01); MM(1, 1, a11, b11); MM(1, 2, a11, b21); MM(1, 3, a11, b31); \
    __builtin_amdgcn_s_setprio(0);                                              \
    BAR();                                                                      \
    f16x8 a20 = LDF256(smA, wm + 32 + fr, 0), a21 = LDF256(smA, wm + 32 + fr, 1); \
    f16x8 a30 = LDF256(smA, wm + 48 + fr, 0), a31 = LDF256(smA, wm + 48 + fr, 1); \
    GLD(gBlo0 + (size_t)(ktB) * 64, &sm[cur][16384 + dst0]);                    \
    GLD(gBlo1 + (size_t)(ktB) * 64, &sm[cur][20480 + dst0]);                    \
    BAR();                                                                      \
    __builtin_amdgcn_s_setprio(1);                                              \
    MM(2, 0, a20, b00); MM(2, 1, a20, b10); MM(2, 2, a20, b20); MM(2, 3, a20, b30); \
    MM(2, 0, a21, b01); MM(2, 1, a21, b11); MM(2, 2, a21, b21); MM(2, 3, a21, b31); \
    MM(3, 0, a30, b00); MM(3, 1, a30, b10); MM(3, 2, a30, b20); MM(3, 3, a30, b30); \
    MM(3, 0, a31, b01); MM(3, 1, a31, b11); MM(3, 2, a31, b21); MM(3, 3, a31, b31); \
    __builtin_amdgcn_s_setprio(0);                                              \
    BAR();                                                                      \
    f16x8 a40 = LDF256(smA, wm + 64 + fr, 0), a41 = LDF256(smA, wm + 64 + fr, 1); \
    f16x8 a50 = LDF256(smA, wm + 80 + fr, 0), a51 = LDF256(smA, wm + 80 + fr, 1); \
    GLD(gBhi0 + (size_t)(ktB) * 64, &sm[cur][24576 + dst0]);                    \
    GLD(gBhi1 + (size_t)(ktB) * 64, &sm[cur][28672 + dst0]);                    \
    BAR();                                                                      \
    __builtin_amdgcn_s_setprio(1);                                              \
    MM(4, 0, a40, b00); MM(4, 1, a40, b10); MM(4, 2, a40, b20); MM(4, 3, a40, b30); \
    MM(4, 0, a41, b01); MM(4, 1, a41, b11); MM(4, 2, a41, b21); MM(4, 3, a41, b31); \
    MM(5, 0, a50, b00); MM(5, 1, a50, b10); MM(5, 2, a50, b20); MM(5, 3, a50, b30); \
    MM(5, 0, a51, b01); MM(5, 1, a51, b11); MM(5, 2, a51, b21); MM(5, 3, a51, b31); \
    __builtin_amdgcn_s_setprio(0);                                              \
    BAR();                                                                      \
    f16x8 a60 = LDF256(smA, wm + 96 + fr, 0),  a61 = LDF256(smA, wm + 96 + fr, 1); \
    f16x8 a70 = LDF256(smA, wm + 112 + fr, 0), a71 = LDF256(smA, wm + 112 + fr, 1); \
    BAR();                                                                      \
    __builtin_amdgcn_s_setprio(1);                                              \
    MM(6, 0, a60, b00); MM(6, 1, a60, b10); MM(6, 2, a60, b20); MM(6, 3, a60, b30); \
    MM(6, 0, a61, b01); MM(6, 1, a61, b11); MM(6, 2, a61, b21); MM(6, 3, a61, b31); \
    MM(7, 0, a70, b00); MM(7, 1, a70, b10); MM(7, 2, a70, b20); MM(7, 3, a70, b30); \
    MM(7, 0, a71, b01); MM(7, 1, a71, b11); MM(7, 2, a71, b21); MM(7, 3, a71, b31); \
    __builtin_amdgcn_s_setprio(0);                                              \
    WAITV4();                                                                   \
    BAR();                                                                      \
} while (0)

    for (int tt = 0; tt < NT; tt += 2) {
        int kb1 = (tt + 2 < NT) ? tt + 2 : NT - 1;
        TILE(0, 1, tt + 1, kb1);
        int ka2 = (tt + 2 < NT) ? tt + 2 : NT - 1;
        int kb2 = (tt + 3 < NT) ? tt + 3 : NT - 1;
        TILE(1, 0, ka2, kb2);
    }
    WAITV0();
#undef TILE

    const int col0 = bn + wn + fr;
#pragma unroll
    for (int mi = 0; mi < 8; mi++) {
        int rb = bm + wm + mi * 16 + fq * 4;
#pragma unroll
        for (int nj = 0; nj < 4; nj++) {
            int col = col0 + nj * 16;
            float bv = bias[col];
#pragma unroll
            for (int r = 0; r < 4; r++) {
                int row = rb + r;
                if (row < M) {
                    float v = acc[mi][nj][r] + bv;
                    if (ACT == 1) v = fmaxf(v, 0.f);
                    if (ACT == 2) v = 0.5f * v * (1.f + erff(v * 0.70710678118f));
                    C[(size_t)row * N + col] = (OUT_T)v;
                }
            }
        }
    }
}

// ===== KERNEL 2: 256x128, BK=32, 8 waves x (64x64), 2 blocks/CU (best for K<=512) ====
// R13-verified: improves conv1/conv2/proj1 by ~130us total vs the 256^2 kernel.
#define LDF128(base, row) \
    (*(const f16x8*)((base) + ((((row) * 64 + fqo)) ^ ((((row) >> 1) & 3) << 4))))

template <int ACT, typename OUT_T>
__global__ __launch_bounds__(512, 4) void k_gemm128(const half_t* __restrict__ A,
                                                    const half_t* __restrict__ W,
                                                    const float* __restrict__ bias,
                                                    OUT_T* __restrict__ C,
                                                    int M, int N, int K) {
    __shared__ half_t sm[36864];   // 3 bufs x (A 8192 + B 4096 halves) = 72KB
    const int gx = gridDim.x;            // N/128
    const int nwg = gx * gridDim.y;
    int b = blockIdx.y * gx + blockIdx.x;
    int w8 = ((nwg & 7) == 0) ? (b & 7) * (nwg >> 3) + (b >> 3) : b;
    const int bn = (w8 % gx) * 128;
    const int bm = (w8 / gx) * 256;

    const int t = threadIdx.x;
    const int w = t >> 6, lane = t & 63;
    const int fr = lane & 15, fq = lane >> 4;
    const int fqo = fq * 16;
    const int wm = (w >> 1) * 64, wn = (w & 1) * 64;
    const int NT = K >> 5;

    int q = w * 512 + lane * 8;
    int s = q ^ (((q >> 6) & 3) << 3);
    int r = s >> 5, c = s & 31;
    const half_t* gAlo = A + (size_t)min(bm + r, M - 1) * K + c;
    const half_t* gAhi = A + (size_t)min(bm + 128 + r, M - 1) * K + c;
    const half_t* gB   = W + (size_t)(bn + r) * K + c;
    const int dst0 = w * 512;

#define STAGE(b3, kt) do {                                                     \
    GLD(gB   + (size_t)(kt) * 32, &sm[(b3) * 12288 + 8192 + dst0]);            \
    GLD(gAlo + (size_t)(kt) * 32, &sm[(b3) * 12288 + dst0]);                   \
    GLD(gAhi + (size_t)(kt) * 32, &sm[(b3) * 12288 + 4096 + dst0]);            \
} while (0)

    f32x4 acc[4][4] = {};

    STAGE(0, 0);
    STAGE(1, (NT > 1) ? 1 : 0);
    WAITV3();
    BAR();

    for (int tt = 0; tt < NT; ++tt) {
        const int cur = tt % 3;
        const int s2 = (tt + 2) % 3;
        const int kt = (tt + 2 < NT) ? tt + 2 : NT - 1;
        const char* smA = (const char*)&sm[cur * 12288];
        const char* smB = smA + 16384;   // 8192 halves
        STAGE(s2, kt);
        f16x8 b0 = LDF128(smB, wn + fr);
        f16x8 b1 = LDF128(smB, wn + 16 + fr);
        f16x8 b2 = LDF128(smB, wn + 32 + fr);
        f16x8 b3 = LDF128(smB, wn + 48 + fr);
        __builtin_amdgcn_s_setprio(1);
#pragma unroll
        for (int mi = 0; mi < 4; mi++) {
            f16x8 a = LDF128(smA, wm + mi * 16 + fr);
            MM(mi, 0, a, b0); MM(mi, 1, a, b1);
            MM(mi, 2, a, b2); MM(mi, 3, a, b3);
        }
        __builtin_amdgcn_s_setprio(0);
        WAITV3();
        BAR();
    }
    WAITV0();
#undef STAGE

    const int col0 = bn + wn + fr;
#pragma unroll
    for (int mi = 0; mi < 4; mi++) {
        int rb = bm + wm + mi * 16 + fq * 4;
#pragma unroll
        for (int nj = 0; nj < 4; nj++) {
            int col = col0 + nj * 16;
            float bv = bias[col];
#pragma unroll
            for (int rr = 0; rr < 4; rr++) {
                int row = rb + rr;
                if (row < M) {
                    float v = acc[mi][nj][rr] + bv;
                    if (ACT == 1) v = fmaxf(v, 0.f);
                    if (ACT == 2) v = 0.5f * v * (1.f + erff(v * 0.70710678118f));
                    C[(size_t)row * N + col] = (OUT_T)v;
                }
            }
        }
    }
}

// ---------------- launch ----------------
extern "C" void kernel_launch(void* const* d_in, const int* in_sizes, int n_in,
                              void* d_out, int out_size, void* d_ws, size_t ws_size,
                              hipStream_t stream) {
    const float* x     = (const float*)d_in[0];
    const int*   eidx  = (const int*)d_in[1];
    const float* gn_w  = (const float*)d_in[2];
    const float* gn_b  = (const float*)d_in[3];
    const float* gn_ms = (const float*)d_in[4];
    const float* w1    = (const float*)d_in[5];
    const float* b1    = (const float*)d_in[6];
    const float* w2    = (const float*)d_in[7];
    const float* b2    = (const float*)d_in[8];
    const float* p1    = (const float*)d_in[9];
    const float* pb1   = (const float*)d_in[10];
    const float* p2    = (const float*)d_in[11];
    const float* pb2   = (const float*)d_in[12];

    const int Nn = in_sizes[0] / D_PROT;   // 50000
    const int E  = in_sizes[1] / 2;        // 400000
    const int M  = Nn;

    char* ws = (char*)d_ws;
    size_t off = 0;
    auto alloc = [&](size_t bytes) {
        void* p = ws + off;
        off += (bytes + 255) & ~(size_t)255;
        return p;
    };
    half_t* w1h    = (half_t*)alloc((size_t)D_PROT * D_PROT * 2);
    half_t* w2h    = (half_t*)alloc((size_t)D_PROT * D_PROT * 2);
    half_t* p1h    = (half_t*)alloc((size_t)D_TEXT * D_PROT * 2);
    half_t* p2h    = (half_t*)alloc((size_t)D_TEXT * D_TEXT * 2);
    int*    deg    = (int*)alloc((size_t)Nn * 4);
    float*  dinv   = (float*)alloc((size_t)Nn * 4);
    int*    rowptr = (int*)alloc((size_t)(Nn + 1) * 4);
    int*    fillc  = (int*)alloc((size_t)Nn * 4);
    int*    bsum   = (int*)alloc(4096);
    int*    boff   = (int*)alloc(4096);
    int*    colidx = (int*)alloc((size_t)E * 4);
    float*  sums   = (float*)alloc(D_PROT * 4);
    float*  sumsq  = (float*)alloc(D_PROT * 4);
    float*  gnab   = (float*)alloc(2 * D_PROT * 4);
    half_t* buf1   = (half_t*)alloc((size_t)Nn * D_PROT * 2);
    half_t* buf2   = (half_t*)alloc((size_t)Nn * D_PROT * 2);
    half_t* big    = (half_t*)alloc((size_t)Nn * D_TEXT * 2);

    const int* esrc = eidx;
    const int* edst = eidx + E;

    hipMemsetAsync(deg, 0, (size_t)Nn * 4, stream);
    hipMemsetAsync(fillc, 0, (size_t)Nn * 4, stream);
    hipMemsetAsync(rowptr, 0, (size_t)(Nn + 1) * 4, stream);
    hipMemsetAsync(sums, 0, D_PROT * 4, stream);
    hipMemsetAsync(sumsq, 0, D_PROT * 4, stream);

    k_cvt4<<<(D_PROT * D_PROT / 4 + 255) / 256, 256, 0, stream>>>(w1, w1h, D_PROT * D_PROT / 4);
    k_cvt4<<<(D_PROT * D_PROT / 4 + 255) / 256, 256, 0, stream>>>(w2, w2h, D_PROT * D_PROT / 4);
    k_cvt4<<<(D_TEXT * D_PROT / 4 + 255) / 256, 256, 0, stream>>>(p1, p1h, D_TEXT * D_PROT / 4);
    k_cvt4<<<(D_TEXT * D_TEXT / 4 + 255) / 256, 256, 0, stream>>>(p2, p2h, D_TEXT * D_TEXT / 4);

    int eb = (E + 255) / 256;
    int nb = (Nn + 255) / 256;
    k_deg<<<eb, 256, 0, stream>>>(edst, E, deg);
    k_dinv<<<nb, 256, 0, stream>>>(deg, dinv, Nn);
    k_blocksum<<<nb, 256, 0, stream>>>(deg, bsum, Nn);
    k_scan_bsum<<<1, 256, 0, stream>>>(bsum, boff, nb);
    k_scan_final<<<nb, 256, 0, stream>>>(deg, boff, rowptr, Nn);
    k_fill<<<eb, 256, 0, stream>>>(esrc, edst, E, rowptr, fillc, colidx);

    k_gnreduce<<<256, 256, 0, stream>>>(x, sums, sumsq, Nn);
    k_gnfinal<<<2, 256, 0, stream>>>(sums, sumsq, gn_w, gn_b, gn_ms, gnab, 1.0f / (float)Nn);
    int n4 = Nn * D_PROT / 4;
    k_gnnorm<<<(n4 + 255) / 256, 256, 0, stream>>>(x, gnab, buf1, n4);

    const int mt256 = (M + 255) / 256;
    const int aggb = (Nn + 3) / 4;

    // conv1: agg -> gemm+relu (256x128 high-occupancy kernel)
    k_agg<<<aggb, 256, 0, stream>>>(buf1, buf2, rowptr, colidx, dinv, Nn);
    {
        dim3 g(D_PROT / 128, mt256);
        k_gemm128<1, half_t><<<g, 512, 0, stream>>>(buf2, w1h, b1, buf1, M, D_PROT, D_PROT);
    }
    // conv2
    k_agg<<<aggb, 256, 0, stream>>>(buf1, buf2, rowptr, colidx, dinv, Nn);
    {
        dim3 g(D_PROT / 128, mt256);
        k_gemm128<1, half_t><<<g, 512, 0, stream>>>(buf2, w2h, b2, buf1, M, D_PROT, D_PROT);
    }
    // proj1 + gelu (256x128 kernel)
    {
        dim3 g(D_TEXT / 128, mt256);
        k_gemm128<2, half_t><<<g, 512, 0, stream>>>(buf1, p1h, pb1, big, M, D_TEXT, D_PROT);
    }
    // proj2 -> fp32 out (256^2 4-phase kernel — best measured for K=2048)
    {
        dim3 g(D_TEXT / 256, mt256);
        k_gemm256<0, float><<<g, 512, 0, stream>>>(big, p2h, pb2, (float*)d_out, M, D_TEXT, D_TEXT);
    }
}